// Round 16
// baseline (151.613 us; speedup 1.0000x reference)
//
#include <hip/hip_runtime.h>
#include <math.h>
#include <float.h>

#define B_    4
#define N_    2048
#define M_    8192
#define CIN_  512
#define COUT_ 256

typedef __attribute__((ext_vector_type(8))) short short8v;   // 8 bf16
typedef __attribute__((ext_vector_type(4))) float f32x4;

// ---------------------------------------------------------------------------
// d_ws handoff: producers store system-scope (sc0 sc1 -> L3 coherence point);
// inv_kernel invalidates XCD L1/L2 before each consumer, so consumers use
// normal cached loads. (Round 4/8/9 lessons.)
// ---------------------------------------------------------------------------
__device__ __forceinline__ void ws_store_f32(float* p, float v) {
    __hip_atomic_store((unsigned int*)p, __float_as_uint(v),
                       __ATOMIC_RELAXED, __HIP_MEMORY_SCOPE_SYSTEM);
}
__device__ __forceinline__ void ws_store_u32(int* p, int v) {
    __hip_atomic_store((unsigned int*)p, (unsigned int)v,
                       __ATOMIC_RELAXED, __HIP_MEMORY_SCOPE_SYSTEM);
}

__global__ __launch_bounds__(64) void inv_kernel() {
    asm volatile("buffer_inv sc0 sc1" ::: "memory");
}

__device__ __forceinline__ unsigned short f2bf(float f) {   // RNE f32->bf16
    unsigned u = __float_as_uint(f);
    u += 0x7fffu + ((u >> 16) & 1u);
    return (unsigned short)(u >> 16);
}

// ---------------------------------------------------------------------------
// bf16-MFMA GEMM body (round-11, validated): 64c x 128m block tile, 4 waves,
// wave tile 32x64 (acc[2][4]), BK=32, fp32->bf16 RNE staging, K-step register
// prefetch. MODE 0 (up): BN+ReLU -> LDS transpose -> sc f1t[n][c].
// MODE 1 (lat): BN+ReLU + 3-NN interp add; nnrec prefetched pre-K-loop.
// ---------------------------------------------------------------------------
template<int K, int MODE>
__device__ __forceinline__ void gemm_body(
    char* raw, int b, int c0, int m0,
    const float* __restrict__ X, const float* __restrict__ W,
    const float* __restrict__ gam, const float* __restrict__ bet,
    const float* __restrict__ mu, const float* __restrict__ var,
    float* __restrict__ dst,
    const float* __restrict__ f1t, const float* __restrict__ nnrec, int Mdim)
{
    char* Ab = raw;            // A: [64 c][40 bf16]   row stride 80 B
    char* Bb = raw + 5120;     // B: [128 m][40 bf16]

    const int tid = threadIdx.x;
    const int l  = tid & 63;
    const int wv = tid >> 6;
    const int wc = wv & 1, wn = wv >> 1;

    f32x4 acc[2][4];
    #pragma unroll
    for (int i = 0; i < 2; ++i)
        #pragma unroll
        for (int j = 0; j < 4; ++j)
            acc[i][j] = (f32x4){0.f, 0.f, 0.f, 0.f};

    const int ksA = tid & 7;
    const int crA = tid >> 3;
    const int kqB = tid >> 5;
    const int mlB = tid & 31;

    float4 ra[4]; float2 rb[4];
    if constexpr (MODE == 1) {
        #pragma unroll
        for (int ni = 0; ni < 4; ++ni) {
            int mg = m0 + wn * 64 + ni * 16 + (l & 15);
            const float* rp = nnrec + ((size_t)b * M_ + mg) * 8;
            ra[ni] = *(const float4*)rp;
            rb[ni] = *(const float2*)(rp + 4);
        }
    }

    float4 wreg[2];
    float  xreg[4][4];
    #pragma unroll
    for (int r = 0; r < 2; ++r)
        wreg[r] = *(const float4*)(W + (size_t)(c0 + crA + 32 * r) * K + ksA * 4);
    #pragma unroll
    for (int jj = 0; jj < 4; ++jj) {
        const float* xp = X + ((size_t)b * K + kqB * 4) * Mdim + m0 + mlB + 32 * jj;
        xreg[jj][0] = xp[0];
        xreg[jj][1] = xp[(size_t)Mdim];
        xreg[jj][2] = xp[(size_t)2 * Mdim];
        xreg[jj][3] = xp[(size_t)3 * Mdim];
    }

    for (int kc = 0; kc < K; kc += 32) {
        #pragma unroll
        for (int r = 0; r < 2; ++r) {
            unsigned lo = f2bf(wreg[r].x) | ((unsigned)f2bf(wreg[r].y) << 16);
            unsigned hi = f2bf(wreg[r].z) | ((unsigned)f2bf(wreg[r].w) << 16);
            *(uint2*)(Ab + (crA + 32 * r) * 80 + ksA * 8) = make_uint2(lo, hi);
        }
        #pragma unroll
        for (int jj = 0; jj < 4; ++jj) {
            unsigned lo = f2bf(xreg[jj][0]) | ((unsigned)f2bf(xreg[jj][1]) << 16);
            unsigned hi = f2bf(xreg[jj][2]) | ((unsigned)f2bf(xreg[jj][3]) << 16);
            *(uint2*)(Bb + (mlB + 32 * jj) * 80 + kqB * 8) = make_uint2(lo, hi);
        }
        if (kc + 32 < K) {
            #pragma unroll
            for (int r = 0; r < 2; ++r)
                wreg[r] = *(const float4*)(W + (size_t)(c0 + crA + 32 * r) * K + (kc + 32) + ksA * 4);
            #pragma unroll
            for (int jj = 0; jj < 4; ++jj) {
                const float* xp = X + ((size_t)b * K + (kc + 32) + kqB * 4) * Mdim + m0 + mlB + 32 * jj;
                xreg[jj][0] = xp[0];
                xreg[jj][1] = xp[(size_t)Mdim];
                xreg[jj][2] = xp[(size_t)2 * Mdim];
                xreg[jj][3] = xp[(size_t)3 * Mdim];
            }
        }
        __syncthreads();
        short8v a[2], bfv[4];
        #pragma unroll
        for (int ci = 0; ci < 2; ++ci)
            a[ci] = *(const short8v*)(Ab + (wc * 32 + ci * 16 + (l & 15)) * 80 + (l >> 4) * 16);
        #pragma unroll
        for (int ni = 0; ni < 4; ++ni)
            bfv[ni] = *(const short8v*)(Bb + (wn * 64 + ni * 16 + (l & 15)) * 80 + (l >> 4) * 16);
        #pragma unroll
        for (int ci = 0; ci < 2; ++ci)
            #pragma unroll
            for (int ni = 0; ni < 4; ++ni)
                acc[ci][ni] = __builtin_amdgcn_mfma_f32_16x16x32_bf16(
                    a[ci], bfv[ni], acc[ci][ni], 0, 0, 0);
        __syncthreads();
    }

    const int lc = (l >> 4) * 4;
    float scA[2][4], shA[2][4];
    #pragma unroll
    for (int ci = 0; ci < 2; ++ci)
        #pragma unroll
        for (int r = 0; r < 4; ++r) {
            int c = c0 + wc * 32 + ci * 16 + lc + r;
            float sc = gam[c] / sqrtf(var[c] + 1e-5f);
            scA[ci][r] = sc;
            shA[ci][r] = bet[c] - mu[c] * sc;
        }

    if constexpr (MODE == 0) {
        float* S = (float*)raw;   // [64][66] f32
        #pragma unroll
        for (int h = 0; h < 2; ++h) {
            if (wn == h) {
                #pragma unroll
                for (int ni = 0; ni < 4; ++ni)
                    #pragma unroll
                    for (int ci = 0; ci < 2; ++ci)
                        #pragma unroll
                        for (int r = 0; r < 4; ++r)
                            S[(ni * 16 + (l & 15)) * 66 + wc * 32 + ci * 16 + lc + r] =
                                fmaxf(acc[ci][ni][r] * scA[ci][r] + shA[ci][r], 0.f);
            }
            __syncthreads();
            #pragma unroll
            for (int i = 0; i < 16; ++i) {
                int e = tid + i * 256;
                int row = e >> 6, c = e & 63;
                ws_store_f32(dst + ((size_t)b * N_ + m0 + h * 64 + row) * COUT_ + c0 + c,
                             S[row * 66 + c]);
            }
            __syncthreads();
        }
    } else {
        #pragma unroll
        for (int ni = 0; ni < 4; ++ni) {
            int mg = m0 + wn * 64 + ni * 16 + (l & 15);
            int   i0 = __float_as_int(ra[ni].x);
            int   i1 = __float_as_int(ra[ni].y);
            int   i2 = __float_as_int(ra[ni].z);
            float w0 = ra[ni].w, w1 = rb[ni].x, w2 = rb[ni].y;
            const float4* g0 = (const float4*)(f1t + ((size_t)b * N_ + i0) * COUT_ + c0 + wc * 32 + lc);
            const float4* g1 = (const float4*)(f1t + ((size_t)b * N_ + i1) * COUT_ + c0 + wc * 32 + lc);
            const float4* g2 = (const float4*)(f1t + ((size_t)b * N_ + i2) * COUT_ + c0 + wc * 32 + lc);
            #pragma unroll
            for (int ci = 0; ci < 2; ++ci) {
                float4 G0 = g0[ci * 4];
                float4 G1 = g1[ci * 4];
                float4 G2 = g2[ci * 4];
                const float* f0 = (const float*)&G0;
                const float* f1 = (const float*)&G1;
                const float* f2 = (const float*)&G2;
                #pragma unroll
                for (int r = 0; r < 4; ++r) {
                    float v = fmaxf(acc[ci][ni][r] * scA[ci][r] + shA[ci][r], 0.f);
                    v = fmaf(w0, f0[r], v);
                    v = fmaf(w1, f1[r], v);
                    v = fmaf(w2, f2[r], v);
                    int c = c0 + wc * 32 + ci * 16 + lc + r;
                    dst[((size_t)b * COUT_ + c) * M_ + mg] = v;
                }
            }
        }
    }
}

__global__ __launch_bounds__(256) void up_kernel(
    const float* __restrict__ x1, const float* __restrict__ w_up,
    const float* __restrict__ g_up, const float* __restrict__ b_up,
    const float* __restrict__ m_up, const float* __restrict__ v_up,
    float* __restrict__ f1t)
{
    __shared__ float4 raw4[1056];
    gemm_body<CIN_, 0>((char*)raw4, blockIdx.z, blockIdx.y * 64, blockIdx.x * 128,
                       x1, w_up, g_up, b_up, m_up, v_up, f1t,
                       nullptr, nullptr, N_);
}

__global__ __launch_bounds__(256) void lat_kernel(
    const float* __restrict__ x2, const float* __restrict__ w_lat,
    const float* __restrict__ g_lat, const float* __restrict__ b_lat,
    const float* __restrict__ m_lat, const float* __restrict__ v_lat,
    const float* __restrict__ f1t, const float* __restrict__ nnrec,
    float* __restrict__ out0)
{
    __shared__ float4 raw4[960];
    gemm_body<COUT_, 1>((char*)raw4, blockIdx.z, blockIdx.y * 64, blockIdx.x * 128,
                        x2, w_lat, g_lat, b_lat, m_lat, v_lat, out0,
                        f1t, nnrec, M_);
}

// ---------------------------------------------------------------------------
// Grid build (validated): one block per batch sorts p1 into cell order
// (8x8x8 cells of 0.5 over [0,4)^3); writes sorted (x,y,z,s1), original
// indices, and 513-entry cell-start table via sc stores.
// ---------------------------------------------------------------------------
__global__ __launch_bounds__(256) void grid_build_kernel(
    const float* __restrict__ p1,
    float* __restrict__ g_sptf, int* __restrict__ g_sidx, int* __restrict__ g_cst)
{
    __shared__ float4 spt[2048];
    __shared__ int    sidx[2048];
    __shared__ int    cnt[512];
    __shared__ int    fill[512];
    __shared__ int    wsum[4];

    const int b = blockIdx.x;
    const int tid = threadIdx.x;

    cnt[tid] = 0; cnt[tid + 256] = 0;
    __syncthreads();

    float xr[8], yr[8], zr[8], sr[8];
    int   cr[8];
    #pragma unroll
    for (int u = 0; u < 8; ++u) {
        int n = u * 256 + tid;
        float x = p1[((size_t)(b * N_) + n) * 3 + 0];
        float y = p1[((size_t)(b * N_) + n) * 3 + 1];
        float z = p1[((size_t)(b * N_) + n) * 3 + 2];
        float t = x * x;
        t = fmaf(y, y, t);
        t = fmaf(z, z, t);
        xr[u] = x; yr[u] = y; zr[u] = z; sr[u] = t;
        int cx = min(max((int)(x * 2.0f), 0), 7);
        int cy = min(max((int)(y * 2.0f), 0), 7);
        int cz = min(max((int)(z * 2.0f), 0), 7);
        int c = (cz * 8 + cy) * 8 + cx;
        cr[u] = c;
        atomicAdd(&cnt[c], 1);
    }
    __syncthreads();

    int v0 = cnt[2 * tid], v1 = cnt[2 * tid + 1];
    int tsum = v0 + v1;
    int sc = tsum;
    #pragma unroll
    for (int o = 1; o < 64; o <<= 1) {
        int nv = __shfl_up(sc, o);
        if ((tid & 63) >= o) sc += nv;
    }
    if ((tid & 63) == 63) wsum[tid >> 6] = sc;
    __syncthreads();
    int wpre = 0;
    for (int w = 0; w < (tid >> 6); ++w) wpre += wsum[w];
    int ex = wpre + sc - tsum;
    __syncthreads();
    cnt[2 * tid]     = ex;
    cnt[2 * tid + 1] = ex + v0;
    fill[2 * tid]     = ex;
    fill[2 * tid + 1] = ex + v0;
    __syncthreads();

    #pragma unroll
    for (int u = 0; u < 8; ++u) {
        int pos = atomicAdd(&fill[cr[u]], 1);
        spt[pos]  = make_float4(xr[u], yr[u], zr[u], sr[u]);
        sidx[pos] = u * 256 + tid;
    }
    __syncthreads();

    #pragma unroll
    for (int u = 0; u < 8; ++u) {
        int i = u * 256 + tid;
        float4 v = spt[i];
        float* gp = g_sptf + ((size_t)b * 2048 + i) * 4;
        ws_store_f32(gp + 0, v.x);
        ws_store_f32(gp + 1, v.y);
        ws_store_f32(gp + 2, v.z);
        ws_store_f32(gp + 3, v.w);
        ws_store_u32(g_sidx + (size_t)b * 2048 + i, sidx[i]);
    }
    ws_store_u32(g_cst + (size_t)b * 513 + tid * 2,     cnt[tid * 2]);
    ws_store_u32(g_cst + (size_t)b * 513 + tid * 2 + 1, cnt[tid * 2 + 1]);
    if (tid == 0) ws_store_u32(g_cst + (size_t)b * 513 + 512, 2048);
}

// ---------------------------------------------------------------------------
// NEW: query sort — counting-sort permutation of the 8192 queries per batch
// by their grid cell. Co-scheduled queries then share cell blocks, making
// three_nn's control flow uniform and its LDS reads broadcast (round-15
// pathology: 8 unrelated queries per wave -> divergence + conflicts + 93%
// stall). Any permutation is output-correct: each query is independent and
// written to its original slot.
// ---------------------------------------------------------------------------
__global__ __launch_bounds__(256) void qsort_kernel(
    const float* __restrict__ p2, int* __restrict__ qperm)
{
    __shared__ int cnt[512];
    __shared__ int fill[512];
    __shared__ int wsum[4];

    const int b = blockIdx.x;
    const int tid = threadIdx.x;

    cnt[tid] = 0; cnt[tid + 256] = 0;
    __syncthreads();

    int cr[32];
    #pragma unroll
    for (int u = 0; u < 32; ++u) {
        int m = u * 256 + tid;
        float x = p2[((size_t)(b * M_) + m) * 3 + 0];
        float y = p2[((size_t)(b * M_) + m) * 3 + 1];
        float z = p2[((size_t)(b * M_) + m) * 3 + 2];
        int cx = min(max((int)(x * 2.0f), 0), 7);
        int cy = min(max((int)(y * 2.0f), 0), 7);
        int cz = min(max((int)(z * 2.0f), 0), 7);
        int c = (cz * 8 + cy) * 8 + cx;
        cr[u] = c;
        atomicAdd(&cnt[c], 1);
    }
    __syncthreads();

    int v0 = cnt[2 * tid], v1 = cnt[2 * tid + 1];
    int tsum = v0 + v1;
    int sc = tsum;
    #pragma unroll
    for (int o = 1; o < 64; o <<= 1) {
        int nv = __shfl_up(sc, o);
        if ((tid & 63) >= o) sc += nv;
    }
    if ((tid & 63) == 63) wsum[tid >> 6] = sc;
    __syncthreads();
    int wpre = 0;
    for (int w = 0; w < (tid >> 6); ++w) wpre += wsum[w];
    int ex = wpre + sc - tsum;
    __syncthreads();
    fill[2 * tid]     = ex;
    fill[2 * tid + 1] = ex + v0;
    __syncthreads();

    #pragma unroll
    for (int u = 0; u < 32; ++u) {
        int pos = atomicAdd(&fill[cr[u]], 1);
        ws_store_u32(qperm + (size_t)b * M_ + pos, u * 256 + tid);
    }
}

// ---------------------------------------------------------------------------
// three_nn: grid scan (round-15, validated correct) + cell-sorted queries.
// 8 lanes/query; per-lane lists stay PRIVATE (disjoint candidate partition);
// merged view computed into copies (T/U) for the coverage predicate/output.
// d^2 bits and lex (d2, idx) selection identical to all validated rounds.
// ---------------------------------------------------------------------------
__device__ __forceinline__ void lex_insert(float e, int j,
    float& D0, float& D1, float& D2, int& I0, int& I1, int& I2)
{
    bool l0 = (e < D0) || (e == D0 && j < I0);
    bool l1 = (e < D1) || (e == D1 && j < I1);
    bool l2 = (e < D2) || (e == D2 && j < I2);
    if (l2) {
        if (l0)      { D2=D1; I2=I1; D1=D0; I1=I0; D0=e; I0=j; }
        else if (l1) { D2=D1; I2=I1; D1=e;  I1=j; }
        else         { D2=e;  I2=j; }
    }
}

__device__ __forceinline__ float coverage2(float qx, float qy, float qz,
                                           int cx, int cy, int cz, int r)
{
    const float INF = 1e30f;
    float dxl = (cx - r <= 0) ? INF : qx - (float)(cx - r) * 0.5f;
    float dxh = (cx + r >= 7) ? INF : (float)(cx + r + 1) * 0.5f - qx;
    float dyl = (cy - r <= 0) ? INF : qy - (float)(cy - r) * 0.5f;
    float dyh = (cy + r >= 7) ? INF : (float)(cy + r + 1) * 0.5f - qy;
    float dzl = (cz - r <= 0) ? INF : qz - (float)(cz - r) * 0.5f;
    float dzh = (cz + r >= 7) ? INF : (float)(cz + r + 1) * 0.5f - qz;
    float rc = fminf(fminf(fminf(dxl, dxh), fminf(dyl, dyh)), fminf(dzl, dzh));
    return rc * rc;
}

#define NN_EVAL(i)                                                           \
    {                                                                        \
        float4 cd = spt[i];                                                  \
        int   cix = sidx[i];                                                 \
        float dot = qx * cd.x;                                               \
        dot = fmaf(qy, cd.y, dot);                                           \
        dot = fmaf(qz, cd.z, dot);                                           \
        float d2 = fmaf(-2.0f, dot, s2 + cd.w);                              \
        d2 = fmaxf(d2, 0.0f);                                                \
        lex_insert(d2, cix, D0, D1, D2, I0, I1, I2);                         \
    }

#define MERGECOPY()                                                          \
    {                                                                        \
        T0 = D0; T1 = D1; T2 = D2; U0 = I0; U1 = I1; U2 = I2;                \
        _Pragma("unroll")                                                    \
        for (int st = 1; st <= 4; st <<= 1) {                                \
            float E0 = __shfl_xor(T0, st), E1 = __shfl_xor(T1, st);          \
            float E2 = __shfl_xor(T2, st);                                   \
            int   J0 = __shfl_xor(U0, st), J1 = __shfl_xor(U1, st);          \
            int   J2 = __shfl_xor(U2, st);                                   \
            lex_insert(E0, J0, T0, T1, T2, U0, U1, U2);                      \
            lex_insert(E1, J1, T0, T1, T2, U0, U1, U2);                      \
            lex_insert(E2, J2, T0, T1, T2, U0, U1, U2);                      \
        }                                                                    \
    }

__global__ __launch_bounds__(256) void three_nn_kernel(
    const float* __restrict__ p2, const int* __restrict__ qperm,
    const float* __restrict__ g_sptf, const int* __restrict__ g_sidx,
    const int* __restrict__ g_cst,
    float* __restrict__ nnrec, float* __restrict__ out1)
{
    __shared__ float4 spt[2048];
    __shared__ int    sidx[2048];
    __shared__ int    cst[513];

    const int b = blockIdx.y;
    const int tid = threadIdx.x;

    #pragma unroll
    for (int u = 0; u < 8; ++u) {
        int i = u * 256 + tid;
        spt[i]  = *(const float4*)(g_sptf + ((size_t)b * 2048 + i) * 4);
        sidx[i] = g_sidx[(size_t)b * 2048 + i];
    }
    for (int i = tid; i < 513; i += 256) cst[i] = g_cst[(size_t)b * 513 + i];
    __syncthreads();

    const int sq = blockIdx.x * 32 + (tid >> 3);      // sorted position
    const int m  = qperm[(size_t)b * M_ + sq];        // original query id
    const int s = tid & 7;
    const size_t pbase = ((size_t)(b * M_) + m) * 3;
    const float qx = p2[pbase + 0], qy = p2[pbase + 1], qz = p2[pbase + 2];
    float s2 = qx * qx;
    s2 = fmaf(qy, qy, s2);
    s2 = fmaf(qz, qz, s2);

    const int cxi = min(max((int)(qx * 2.0f), 0), 7);
    const int cyi = min(max((int)(qy * 2.0f), 0), 7);
    const int czi = min(max((int)(qz * 2.0f), 0), 7);

    float D0 = FLT_MAX, D1 = FLT_MAX, D2 = FLT_MAX;
    int   I0 = 0x7fffffff, I1 = 0x7fffffff, I2 = 0x7fffffff;
    float T0, T1, T2;
    int   U0, U1, U2;

    // 3x3x3 block: 9 contiguous row ranges, lanes stride-8 within each
    {
        int x0 = max(cxi - 1, 0), x1 = min(cxi + 1, 7);
        #pragma unroll
        for (int dz = -1; dz <= 1; ++dz) {
            int z = czi + dz;
            if ((unsigned)z > 7u) continue;
            #pragma unroll
            for (int dy = -1; dy <= 1; ++dy) {
                int y = cyi + dy;
                if ((unsigned)y > 7u) continue;
                int row = (z * 8 + y) * 8;
                int st = cst[row + x0], en = cst[row + x1 + 1];
                for (int i = st + s; i < en; i += 8) NN_EVAL(i)
            }
        }
    }
    MERGECOPY()

    // coverage check + rare ring expansion; per-lane lists stay disjoint,
    // merged view recomputed into copies after each ring
    float rcov2 = coverage2(qx, qy, qz, cxi, cyi, czi, 1);
    int r = 2;
    while (T2 >= rcov2 * 0.999f && r <= 7) {
        for (int dz = -r; dz <= r; ++dz) {
            int z = czi + dz;
            if ((unsigned)z > 7u) continue;
            for (int dy = -r; dy <= r; ++dy) {
                int y = cyi + dy;
                if ((unsigned)y > 7u) continue;
                int row = (z * 8 + y) * 8;
                bool edge = (dz == r) || (dz == -r) || (dy == r) || (dy == -r);
                if (edge) {
                    int x0 = max(cxi - r, 0), x1 = min(cxi + r, 7);
                    int st = cst[row + x0], en = cst[row + x1 + 1];
                    for (int i = st + s; i < en; i += 8) NN_EVAL(i)
                } else {
                    for (int sgn = -1; sgn <= 1; sgn += 2) {
                        int x = cxi + sgn * r;
                        if ((unsigned)x > 7u) continue;
                        int st = cst[row + x], en = cst[row + x + 1];
                        for (int i = st + s; i < en; i += 8) NN_EVAL(i)
                    }
                }
            }
        }
        MERGECOPY()
        rcov2 = coverage2(qx, qy, qz, cxi, cyi, czi, r);
        ++r;
    }

    if (s == 0) {
        float r0 = 1.0f / (T0 + 1e-8f);
        float r1 = 1.0f / (T1 + 1e-8f);
        float r2 = 1.0f / (T2 + 1e-8f);
        float sum = (r0 + r1) + r2;
        float* rp = nnrec + ((size_t)(b * M_) + m) * 8;
        ws_store_u32((int*)rp + 0, U0);
        ws_store_u32((int*)rp + 1, U1);
        ws_store_u32((int*)rp + 2, U2);
        ws_store_f32(rp + 3, r0 / sum);
        ws_store_f32(rp + 4, r1 / sum);
        ws_store_f32(rp + 5, r2 / sum);
        size_t o = ((size_t)(b * M_) + m) * 3;
        out1[o + 0] = qx; out1[o + 1] = qy; out1[o + 2] = qz;
    }
}

// ---------------------------------------------------------------------------
extern "C" void kernel_launch(void* const* d_in, const int* in_sizes, int n_in,
                              void* d_out, int out_size, void* d_ws, size_t ws_size,
                              hipStream_t stream)
{
    (void)in_sizes; (void)n_in; (void)out_size; (void)ws_size;

    const float* x1    = (const float*)d_in[0];
    const float* p1    = (const float*)d_in[1];
    const float* x2    = (const float*)d_in[2];
    const float* p2    = (const float*)d_in[3];
    const float* w_up  = (const float*)d_in[4];
    const float* g_up  = (const float*)d_in[5];
    const float* b_up  = (const float*)d_in[6];
    const float* m_up  = (const float*)d_in[7];
    const float* v_up  = (const float*)d_in[8];
    const float* w_lat = (const float*)d_in[9];
    const float* g_lat = (const float*)d_in[10];
    const float* b_lat = (const float*)d_in[11];
    const float* m_lat = (const float*)d_in[12];
    const float* v_lat = (const float*)d_in[13];

    float* out0 = (float*)d_out;
    float* out1 = out0 + (size_t)B_ * COUT_ * M_;   // p2 passthrough

    // ws layout: f1t (8MB) | nnrec (1MB) | g_spt (128KB) | g_sidx (32KB) |
    //            g_cst (~8.2KB) | qperm (128KB)
    float* f1t    = (float*)d_ws;
    float* nnrec  = f1t + (size_t)B_ * N_ * COUT_;
    float* g_sptf = nnrec + (size_t)B_ * M_ * 8;
    int*   g_sidx = (int*)(g_sptf + (size_t)B_ * 2048 * 4);
    int*   g_cst  = g_sidx + (size_t)B_ * 2048;
    int*   qperm  = g_cst + (size_t)B_ * 513;

    grid_build_kernel<<<dim3(B_), 256, 0, stream>>>(p1, g_sptf, g_sidx, g_cst);

    qsort_kernel<<<dim3(B_), 256, 0, stream>>>(p2, qperm);

    up_kernel<<<dim3(N_ / 128, COUT_ / 64, B_), 256, 0, stream>>>(
        x1, w_up, g_up, b_up, m_up, v_up, f1t);

    inv_kernel<<<dim3(512), 64, 0, stream>>>();

    three_nn_kernel<<<dim3(M_ / 32, B_), 256, 0, stream>>>(
        p2, qperm, g_sptf, g_sidx, g_cst, nnrec, out1);

    inv_kernel<<<dim3(512), 64, 0, stream>>>();

    lat_kernel<<<dim3(M_ / 128, COUT_ / 64, B_), 256, 0, stream>>>(
        x2, w_lat, g_lat, b_lat, m_lat, v_lat, f1t, nnrec, out0);
}

// Round 17
// 93.974 us; speedup vs baseline: 1.6133x; 1.6133x over previous
//
#include <hip/hip_runtime.h>
#include <math.h>
#include <float.h>

#define B_    4
#define N_    2048
#define M_    8192
#define CIN_  512
#define COUT_ 256

typedef __attribute__((ext_vector_type(8))) short short8v;   // 8 bf16
typedef __attribute__((ext_vector_type(4))) float f32x4;

// ---------------------------------------------------------------------------
// d_ws handoff: producers store system-scope (sc0 sc1 -> L3 coherence point);
// one inv_kernel invalidates XCD L1/L2 before the consumer, so consumers use
// normal cached loads. (Round 4/8/9 lessons.)
// ---------------------------------------------------------------------------
__device__ __forceinline__ void ws_store_f32(float* p, float v) {
    __hip_atomic_store((unsigned int*)p, __float_as_uint(v),
                       __ATOMIC_RELAXED, __HIP_MEMORY_SCOPE_SYSTEM);
}
__device__ __forceinline__ void ws_store_u32(int* p, int v) {
    __hip_atomic_store((unsigned int*)p, (unsigned int)v,
                       __ATOMIC_RELAXED, __HIP_MEMORY_SCOPE_SYSTEM);
}

__global__ __launch_bounds__(64) void inv_kernel() {
    asm volatile("buffer_inv sc0 sc1" ::: "memory");
}

__device__ __forceinline__ unsigned short f2bf(float f) {   // RNE f32->bf16
    unsigned u = __float_as_uint(f);
    u += 0x7fffu + ((u >> 16) & 1u);
    return (unsigned short)(u >> 16);
}

// ---------------------------------------------------------------------------
// bf16-MFMA GEMM body (round-11, validated): 64c x 128m block tile, 4 waves,
// wave tile 32x64 (acc[2][4]), BK=32, fp32->bf16 RNE staging, K-step register
// prefetch. MODE 0 (up): BN+ReLU -> LDS transpose -> sc f1t[n][c].
// MODE 1 (lat): BN+ReLU + 3-NN interp add; nnrec prefetched pre-K-loop.
// ---------------------------------------------------------------------------
template<int K, int MODE>
__device__ __forceinline__ void gemm_body(
    char* raw, int b, int c0, int m0,
    const float* __restrict__ X, const float* __restrict__ W,
    const float* __restrict__ gam, const float* __restrict__ bet,
    const float* __restrict__ mu, const float* __restrict__ var,
    float* __restrict__ dst,
    const float* __restrict__ f1t, const float* __restrict__ nnrec, int Mdim)
{
    char* Ab = raw;            // A: [64 c][40 bf16]   row stride 80 B
    char* Bb = raw + 5120;     // B: [128 m][40 bf16]

    const int tid = threadIdx.x;
    const int l  = tid & 63;
    const int wv = tid >> 6;
    const int wc = wv & 1, wn = wv >> 1;

    f32x4 acc[2][4];
    #pragma unroll
    for (int i = 0; i < 2; ++i)
        #pragma unroll
        for (int j = 0; j < 4; ++j)
            acc[i][j] = (f32x4){0.f, 0.f, 0.f, 0.f};

    const int ksA = tid & 7;
    const int crA = tid >> 3;
    const int kqB = tid >> 5;
    const int mlB = tid & 31;

    float4 ra[4]; float2 rb[4];
    if constexpr (MODE == 1) {
        #pragma unroll
        for (int ni = 0; ni < 4; ++ni) {
            int mg = m0 + wn * 64 + ni * 16 + (l & 15);
            const float* rp = nnrec + ((size_t)b * M_ + mg) * 8;
            ra[ni] = *(const float4*)rp;
            rb[ni] = *(const float2*)(rp + 4);
        }
    }

    float4 wreg[2];
    float  xreg[4][4];
    #pragma unroll
    for (int r = 0; r < 2; ++r)
        wreg[r] = *(const float4*)(W + (size_t)(c0 + crA + 32 * r) * K + ksA * 4);
    #pragma unroll
    for (int jj = 0; jj < 4; ++jj) {
        const float* xp = X + ((size_t)b * K + kqB * 4) * Mdim + m0 + mlB + 32 * jj;
        xreg[jj][0] = xp[0];
        xreg[jj][1] = xp[(size_t)Mdim];
        xreg[jj][2] = xp[(size_t)2 * Mdim];
        xreg[jj][3] = xp[(size_t)3 * Mdim];
    }

    for (int kc = 0; kc < K; kc += 32) {
        #pragma unroll
        for (int r = 0; r < 2; ++r) {
            unsigned lo = f2bf(wreg[r].x) | ((unsigned)f2bf(wreg[r].y) << 16);
            unsigned hi = f2bf(wreg[r].z) | ((unsigned)f2bf(wreg[r].w) << 16);
            *(uint2*)(Ab + (crA + 32 * r) * 80 + ksA * 8) = make_uint2(lo, hi);
        }
        #pragma unroll
        for (int jj = 0; jj < 4; ++jj) {
            unsigned lo = f2bf(xreg[jj][0]) | ((unsigned)f2bf(xreg[jj][1]) << 16);
            unsigned hi = f2bf(xreg[jj][2]) | ((unsigned)f2bf(xreg[jj][3]) << 16);
            *(uint2*)(Bb + (mlB + 32 * jj) * 80 + kqB * 8) = make_uint2(lo, hi);
        }
        if (kc + 32 < K) {
            #pragma unroll
            for (int r = 0; r < 2; ++r)
                wreg[r] = *(const float4*)(W + (size_t)(c0 + crA + 32 * r) * K + (kc + 32) + ksA * 4);
            #pragma unroll
            for (int jj = 0; jj < 4; ++jj) {
                const float* xp = X + ((size_t)b * K + (kc + 32) + kqB * 4) * Mdim + m0 + mlB + 32 * jj;
                xreg[jj][0] = xp[0];
                xreg[jj][1] = xp[(size_t)Mdim];
                xreg[jj][2] = xp[(size_t)2 * Mdim];
                xreg[jj][3] = xp[(size_t)3 * Mdim];
            }
        }
        __syncthreads();
        short8v a[2], bfv[4];
        #pragma unroll
        for (int ci = 0; ci < 2; ++ci)
            a[ci] = *(const short8v*)(Ab + (wc * 32 + ci * 16 + (l & 15)) * 80 + (l >> 4) * 16);
        #pragma unroll
        for (int ni = 0; ni < 4; ++ni)
            bfv[ni] = *(const short8v*)(Bb + (wn * 64 + ni * 16 + (l & 15)) * 80 + (l >> 4) * 16);
        #pragma unroll
        for (int ci = 0; ci < 2; ++ci)
            #pragma unroll
            for (int ni = 0; ni < 4; ++ni)
                acc[ci][ni] = __builtin_amdgcn_mfma_f32_16x16x32_bf16(
                    a[ci], bfv[ni], acc[ci][ni], 0, 0, 0);
        __syncthreads();
    }

    const int lc = (l >> 4) * 4;
    float scA[2][4], shA[2][4];
    #pragma unroll
    for (int ci = 0; ci < 2; ++ci)
        #pragma unroll
        for (int r = 0; r < 4; ++r) {
            int c = c0 + wc * 32 + ci * 16 + lc + r;
            float sc = gam[c] / sqrtf(var[c] + 1e-5f);
            scA[ci][r] = sc;
            shA[ci][r] = bet[c] - mu[c] * sc;
        }

    if constexpr (MODE == 0) {
        float* S = (float*)raw;   // [64][66] f32
        #pragma unroll
        for (int h = 0; h < 2; ++h) {
            if (wn == h) {
                #pragma unroll
                for (int ni = 0; ni < 4; ++ni)
                    #pragma unroll
                    for (int ci = 0; ci < 2; ++ci)
                        #pragma unroll
                        for (int r = 0; r < 4; ++r)
                            S[(ni * 16 + (l & 15)) * 66 + wc * 32 + ci * 16 + lc + r] =
                                fmaxf(acc[ci][ni][r] * scA[ci][r] + shA[ci][r], 0.f);
            }
            __syncthreads();
            #pragma unroll
            for (int i = 0; i < 16; ++i) {
                int e = tid + i * 256;
                int row = e >> 6, c = e & 63;
                ws_store_f32(dst + ((size_t)b * N_ + m0 + h * 64 + row) * COUT_ + c0 + c,
                             S[row * 66 + c]);
            }
            __syncthreads();
        }
    } else {
        #pragma unroll
        for (int ni = 0; ni < 4; ++ni) {
            int mg = m0 + wn * 64 + ni * 16 + (l & 15);
            int   i0 = __float_as_int(ra[ni].x);
            int   i1 = __float_as_int(ra[ni].y);
            int   i2 = __float_as_int(ra[ni].z);
            float w0 = ra[ni].w, w1 = rb[ni].x, w2 = rb[ni].y;
            const float4* g0 = (const float4*)(f1t + ((size_t)b * N_ + i0) * COUT_ + c0 + wc * 32 + lc);
            const float4* g1 = (const float4*)(f1t + ((size_t)b * N_ + i1) * COUT_ + c0 + wc * 32 + lc);
            const float4* g2 = (const float4*)(f1t + ((size_t)b * N_ + i2) * COUT_ + c0 + wc * 32 + lc);
            #pragma unroll
            for (int ci = 0; ci < 2; ++ci) {
                float4 G0 = g0[ci * 4];
                float4 G1 = g1[ci * 4];
                float4 G2 = g2[ci * 4];
                const float* f0 = (const float*)&G0;
                const float* f1 = (const float*)&G1;
                const float* f2 = (const float*)&G2;
                #pragma unroll
                for (int r = 0; r < 4; ++r) {
                    float v = fmaxf(acc[ci][ni][r] * scA[ci][r] + shA[ci][r], 0.f);
                    v = fmaf(w0, f0[r], v);
                    v = fmaf(w1, f1[r], v);
                    v = fmaf(w2, f2[r], v);
                    int c = c0 + wc * 32 + ci * 16 + lc + r;
                    dst[((size_t)b * COUT_ + c) * M_ + mg] = v;
                }
            }
        }
    }
}

__global__ __launch_bounds__(256) void up_kernel(
    const float* __restrict__ x1, const float* __restrict__ w_up,
    const float* __restrict__ g_up, const float* __restrict__ b_up,
    const float* __restrict__ m_up, const float* __restrict__ v_up,
    float* __restrict__ f1t)
{
    __shared__ float4 raw4[1056];
    gemm_body<CIN_, 0>((char*)raw4, blockIdx.z, blockIdx.y * 64, blockIdx.x * 128,
                       x1, w_up, g_up, b_up, m_up, v_up, f1t,
                       nullptr, nullptr, N_);
}

__global__ __launch_bounds__(256) void lat_kernel(
    const float* __restrict__ x2, const float* __restrict__ w_lat,
    const float* __restrict__ g_lat, const float* __restrict__ b_lat,
    const float* __restrict__ m_lat, const float* __restrict__ v_lat,
    const float* __restrict__ f1t, const float* __restrict__ nnrec,
    float* __restrict__ out0)
{
    __shared__ float4 raw4[960];
    gemm_body<COUT_, 1>((char*)raw4, blockIdx.z, blockIdx.y * 64, blockIdx.x * 128,
                        x2, w_lat, g_lat, b_lat, m_lat, v_lat, out0,
                        f1t, nnrec, M_);
}

// ---------------------------------------------------------------------------
// three_nn (round-10 EXACT structure — best measured: 51.5us, VALUBusy 73%):
// 8 lanes/query over disjoint 256-candidate segments; chunks of 8 read as
// b128 from padded LDS with REGISTER PING-PONG prefetch; single branchless
// bubble-insert chain per lane (ascending scan -> strict < is stable);
// butterfly merge with lexicographic (d2, idx). d^2 bits identical to the
// validated formula:
//   s = fma(z,z, fma(y,y, x*x)); dot likewise; d2 = max(fma(-2,dot,s2+s1),0)
// (Grid variants r12-r16: 15x less work but latency-hosed at 75-172us —
//  reverted per round-15 pre-commitment.)
// ---------------------------------------------------------------------------
__device__ __forceinline__ void lex_insert(float e, int j,
    float& D0, float& D1, float& D2, int& I0, int& I1, int& I2)
{
    bool l0 = (e < D0) || (e == D0 && j < I0);
    bool l1 = (e < D1) || (e == D1 && j < I1);
    bool l2 = (e < D2) || (e == D2 && j < I2);
    if (l2) {
        if (l0)      { D2=D1; I2=I1; D1=D0; I1=I0; D0=e; I0=j; }
        else if (l1) { D2=D1; I2=I1; D1=e;  I1=j; }
        else         { D2=e;  I2=j; }
    }
}

__device__ __forceinline__ void bubble_insert(float e, int ie,
    float& D0, float& D1, float& D2, int& I0, int& I1, int& I2)
{
    bool l2 = e < D2;
    D2 = l2 ? e  : D2;
    I2 = l2 ? ie : I2;
    bool s1 = D2 < D1;
    float tf = D1; int ti = I1;
    D1 = s1 ? D2 : D1;  I1 = s1 ? I2 : I1;
    D2 = s1 ? tf : D2;  I2 = s1 ? ti : I2;
    bool s0 = D1 < D0;
    tf = D0; ti = I0;
    D0 = s0 ? D1 : D0;  I0 = s0 ? I1 : I0;
    D1 = s0 ? tf : D1;  I1 = s0 ? ti : I1;
}

__global__ __launch_bounds__(256) void three_nn_kernel(
    const float* __restrict__ p1, const float* __restrict__ p2,
    float* __restrict__ nnrec, float* __restrict__ out1)
{
    __shared__ float4 P[8][257];
    const int b = blockIdx.y;
    #pragma unroll
    for (int r = 0; r < 8; ++r) {
        int n = r * 256 + threadIdx.x;
        float x = p1[((size_t)(b*N_)+n)*3 + 0];
        float y = p1[((size_t)(b*N_)+n)*3 + 1];
        float z = p1[((size_t)(b*N_)+n)*3 + 2];
        float t = x * x;
        t = fmaf(y, y, t);
        t = fmaf(z, z, t);
        P[r][threadIdx.x] = make_float4(x, y, z, t);
    }
    __syncthreads();

    const int m = blockIdx.x * 32 + (threadIdx.x >> 3);
    const int s = threadIdx.x & 7;
    const size_t pbase = ((size_t)(b*M_) + m) * 3;
    const float qx = p2[pbase+0], qy = p2[pbase+1], qz = p2[pbase+2];
    float s2 = qx * qx;
    s2 = fmaf(qy, qy, s2);
    s2 = fmaf(qz, qz, s2);

    float D0 = FLT_MAX, D1 = FLT_MAX, D2 = FLT_MAX;
    int   I0 = 0x7fffffff, I1 = 0x7fffffff, I2 = 0x7fffffff;
    const int base = s * 256;
    const float4* Ps = &P[s][0];

    float4 ca[8], cb[8];
    #pragma unroll
    for (int u = 0; u < 8; ++u) ca[u] = Ps[u];

    #define PROC(CV, IB)                                                     \
        {                                                                    \
            float d[8];                                                      \
            _Pragma("unroll")                                                \
            for (int u = 0; u < 8; ++u) {                                    \
                float dot = qx * CV[u].x;                                    \
                dot = fmaf(qy, CV[u].y, dot);                                \
                dot = fmaf(qz, CV[u].z, dot);                                \
                float d2 = fmaf(-2.0f, dot, s2 + CV[u].w);                   \
                d[u] = fmaxf(d2, 0.0f);                                      \
            }                                                                \
            _Pragma("unroll")                                                \
            for (int u = 0; u < 8; ++u)                                      \
                bubble_insert(d[u], (IB) + u, D0, D1, D2, I0, I1, I2);       \
        }

    for (int j = 0; j < 32; j += 2) {
        #pragma unroll
        for (int u = 0; u < 8; ++u) cb[u] = Ps[(j + 1) * 8 + u];
        PROC(ca, base + j * 8);
        if (j + 2 < 32) {
            #pragma unroll
            for (int u = 0; u < 8; ++u) ca[u] = Ps[(j + 2) * 8 + u];
        }
        PROC(cb, base + (j + 1) * 8);
    }
    #undef PROC

    #pragma unroll
    for (int st = 1; st <= 4; st <<= 1) {
        float E0 = __shfl_xor(D0, st), E1 = __shfl_xor(D1, st), E2 = __shfl_xor(D2, st);
        int   J0 = __shfl_xor(I0, st), J1 = __shfl_xor(I1, st), J2 = __shfl_xor(I2, st);
        lex_insert(E0, J0, D0, D1, D2, I0, I1, I2);
        lex_insert(E1, J1, D0, D1, D2, I0, I1, I2);
        lex_insert(E2, J2, D0, D1, D2, I0, I1, I2);
    }
    if (s == 0) {
        float r0 = 1.0f / (D0 + 1e-8f);
        float r1 = 1.0f / (D1 + 1e-8f);
        float r2 = 1.0f / (D2 + 1e-8f);
        float sum = (r0 + r1) + r2;
        float* rp = nnrec + ((size_t)(b*M_) + m) * 8;
        ws_store_u32((int*)rp + 0, I0);
        ws_store_u32((int*)rp + 1, I1);
        ws_store_u32((int*)rp + 2, I2);
        ws_store_f32(rp + 3, r0 / sum);
        ws_store_f32(rp + 4, r1 / sum);
        ws_store_f32(rp + 5, r2 / sum);
        size_t o = ((size_t)(b*M_) + m) * 3;
        out1[o+0] = qx; out1[o+1] = qy; out1[o+2] = qz;
    }
}

// ---------------------------------------------------------------------------
extern "C" void kernel_launch(void* const* d_in, const int* in_sizes, int n_in,
                              void* d_out, int out_size, void* d_ws, size_t ws_size,
                              hipStream_t stream)
{
    (void)in_sizes; (void)n_in; (void)out_size; (void)ws_size;

    const float* x1    = (const float*)d_in[0];
    const float* p1    = (const float*)d_in[1];
    const float* x2    = (const float*)d_in[2];
    const float* p2    = (const float*)d_in[3];
    const float* w_up  = (const float*)d_in[4];
    const float* g_up  = (const float*)d_in[5];
    const float* b_up  = (const float*)d_in[6];
    const float* m_up  = (const float*)d_in[7];
    const float* v_up  = (const float*)d_in[8];
    const float* w_lat = (const float*)d_in[9];
    const float* g_lat = (const float*)d_in[10];
    const float* b_lat = (const float*)d_in[11];
    const float* m_lat = (const float*)d_in[12];
    const float* v_lat = (const float*)d_in[13];

    float* out0 = (float*)d_out;
    float* out1 = out0 + (size_t)B_ * COUT_ * M_;   // p2 passthrough

    // workspace layout: f1t (8 MB) | nnrec (1 MB, 8 floats per query)
    float* f1t   = (float*)d_ws;
    float* nnrec = f1t + (size_t)B_ * N_ * COUT_;

    up_kernel<<<dim3(N_ / 128, COUT_ / 64, B_), 256, 0, stream>>>(
        x1, w_up, g_up, b_up, m_up, v_up, f1t);

    three_nn_kernel<<<dim3(M_ / 32, B_), 256, 0, stream>>>(
        p1, p2, nnrec, out1);

    inv_kernel<<<dim3(512), 64, 0, stream>>>();

    lat_kernel<<<dim3(M_ / 128, COUT_ / 64, B_), 256, 0, stream>>>(
        x2, w_lat, g_lat, b_lat, m_lat, v_lat, f1t, nnrec, out0);
}